// Round 2
// baseline (390.862 us; speedup 1.0000x reference)
//
#include <hip/hip_runtime.h>

typedef unsigned short u16;
typedef __attribute__((ext_vector_type(8))) short s16x8;
typedef __attribute__((ext_vector_type(8))) unsigned short u16x8;
typedef __attribute__((ext_vector_type(4))) float f32x4;

#define SEQ 2048
#define KEXP 0.18033688011112042f  /* 0.125 * log2(e) */

__device__ __forceinline__ float bf2f(u16 x) {
  union { unsigned u; float f; } c; c.u = ((unsigned)x) << 16; return c.f;
}
__device__ __forceinline__ u16 f2bf(float f) {
  union { float f; unsigned u; } c; c.f = f;
  unsigned u = c.u;
  return (u16)((u + 0x7fffu + ((u >> 16) & 1u)) >> 16);
}

// ---------------- fp32 -> bf16 flat convert ----------------
__global__ __launch_bounds__(256) void k_cvt(const float* __restrict__ src,
                                             u16* __restrict__ dst, int n4) {
  int i = blockIdx.x * 256 + threadIdx.x;
  if (i >= n4) return;
  float4 v = ((const float4*)src)[i];
  ((ushort4*)dst)[i] = make_ushort4(f2bf(v.x), f2bf(v.y), f2bf(v.z), f2bf(v.w));
}

// ---------------- fp32 [R][C] -> bf16 [C][R] transpose-convert ----------------
__global__ __launch_bounds__(256) void k_tcvt(const float* __restrict__ src,
                                              u16* __restrict__ dst, int R, int C) {
  __shared__ u16 T[64][72];
  int r0 = blockIdx.y * 64, c0 = blockIdx.x * 64;
  int tid = threadIdx.x;
#pragma unroll
  for (int p = 0; p < 4; ++p) {
    int f = p * 256 + tid;            // float4 id within 64x64 tile
    int r = f >> 4, cc = (f & 15) * 4;
    float4 v = *(const float4*)(src + (size_t)(r0 + r) * C + c0 + cc);
    T[r][cc + 0] = f2bf(v.x); T[r][cc + 1] = f2bf(v.y);
    T[r][cc + 2] = f2bf(v.z); T[r][cc + 3] = f2bf(v.w);
  }
  __syncthreads();
#pragma unroll
  for (int p = 0; p < 2; ++p) {
    int f = p * 256 + tid;            // u16x8 chunk id
    int c = f >> 3, rr = (f & 7) * 8;
    u16x8 v;
#pragma unroll
    for (int e = 0; e < 8; ++e) v[e] = T[rr + e][c];
    *(u16x8*)(dst + (size_t)(c0 + c) * R + r0 + rr) = v;
  }
}

// ---------------- C[M,N] = A[M,K] @ Bt[N,K]^T  (bf16 in, bf16 or f32+res out) ----
template <int RES>
__global__ __launch_bounds__(256) void k_gemm_bt(const u16* __restrict__ A,
                                                 const u16* __restrict__ Bt,
                                                 u16* __restrict__ Cb,
                                                 float* __restrict__ Cf,
                                                 const float* __restrict__ res,
                                                 int M, int N, int K) {
  __shared__ u16 As[128 * 72];
  __shared__ u16 Bs[128 * 72];
  const int tid = threadIdx.x;
  const int l = tid & 63, wv = tid >> 6;
  const int g = l >> 4, c16 = l & 15;
  const int m0 = blockIdx.x * 128, n0 = blockIdx.y * 128;
  const int wr = (wv >> 1) * 64, wc = (wv & 1) * 64;
  f32x4 acc[4][4] = {};
  for (int k0 = 0; k0 < K; k0 += 64) {
    __syncthreads();
    // 128 rows x 64 k = 1024 16B-chunks per matrix; 256 threads -> 4 iters
#pragma unroll
    for (int p = 0; p < 4; ++p) {
      int f = p * 256 + tid;
      int row = f >> 3, kb = (f & 7) * 8;
      u16x8 va = *(const u16x8*)(A + (size_t)(m0 + row) * K + k0 + kb);
      u16x8 vb = *(const u16x8*)(Bt + (size_t)(n0 + row) * K + k0 + kb);
      *(u16x8*)&As[row * 72 + kb] = va;
      *(u16x8*)&Bs[row * 72 + kb] = vb;
    }
    __syncthreads();
#pragma unroll
    for (int ks = 0; ks < 2; ++ks) {
      s16x8 af[4], bf[4];
#pragma unroll
      for (int fr = 0; fr < 4; ++fr)
        af[fr] = *(const s16x8*)&As[(wr + fr * 16 + c16) * 72 + ks * 32 + g * 8];
#pragma unroll
      for (int fc = 0; fc < 4; ++fc)
        bf[fc] = *(const s16x8*)&Bs[(wc + fc * 16 + c16) * 72 + ks * 32 + g * 8];
#pragma unroll
      for (int fr = 0; fr < 4; ++fr)
#pragma unroll
        for (int fc = 0; fc < 4; ++fc)
          acc[fr][fc] = __builtin_amdgcn_mfma_f32_16x16x32_bf16(af[fr], bf[fc],
                                                                acc[fr][fc], 0, 0, 0);
    }
  }
#pragma unroll
  for (int fr = 0; fr < 4; ++fr)
#pragma unroll
    for (int fc = 0; fc < 4; ++fc)
#pragma unroll
      for (int reg = 0; reg < 4; ++reg) {
        int row = m0 + wr + fr * 16 + g * 4 + reg;
        int col = n0 + wc + fc * 16 + c16;
        float v = acc[fr][fc][reg];
        if (RES) Cf[(size_t)row * N + col] = v + res[(size_t)row * N + col];
        else     Cb[(size_t)row * N + col] = f2bf(v);
      }
}

// ---------------- build V^T [b][n][d][j] from qkv ----------------
__global__ __launch_bounds__(256) void k_vt(const u16* __restrict__ qkv,
                                            u16* __restrict__ vT) {
  __shared__ u16 T[64][72];
  const int tid = threadIdx.x;
  const int j0 = blockIdx.x * 64;
  const int n = blockIdx.y & 15, b = blockIdx.y >> 4;
#pragma unroll
  for (int p = 0; p < 2; ++p) {
    int f = p * 256 + tid;
    int r = f >> 3, cc = (f & 7) * 8;
    *(u16x8*)&T[r][cc] =
        *(const u16x8*)(qkv + ((size_t)((j0 + r) * 2 + b)) * 3072 + 2048 + n * 64 + cc);
  }
  __syncthreads();
#pragma unroll
  for (int p = 0; p < 2; ++p) {
    int f = p * 256 + tid;
    int d = f >> 3, jc = (f & 7) * 8;
    u16x8 v;
#pragma unroll
    for (int e = 0; e < 8; ++e) v[e] = T[jc + e][d];
    *(u16x8*)(vT + ((size_t)((b * 16 + n) * 64 + d)) * 2048 + j0 + jc) = v;
  }
}

// ---------------- fused rel-attention (flash-style) ----------------
__global__ __launch_bounds__(256) void k_attn(const u16* __restrict__ qkv,
                                              const u16* __restrict__ rk,
                                              const u16* __restrict__ vT,
                                              const float* __restrict__ rwb,
                                              const float* __restrict__ rrb,
                                              u16* __restrict__ av) {
  __shared__ u16 Qp[80][72];    // Q + r_r_bias rows i0..i0+79
  __shared__ u16 Kt[64][72];    // K tile [j][d]
  __shared__ u16 Vt[64][72];    // V^T tile [d][j]
  __shared__ u16 Rb[128][72];   // r_k band [w][d], w -> u = j0-i0-63+w
  __shared__ u16 QRs[80][136];  // QR band output bf16
  __shared__ u16 Pt[64][72];    // P (probs) bf16

  const int tid = threadIdx.x;
  const int l = tid & 63, wv = tid >> 6;
  const int g = l >> 4, c16 = l & 15;
  const int i0 = blockIdx.x * 64;
  const int n = blockIdx.y & 15, b = blockIdx.y >> 4;
  const f32x4 zero4 = {0.f, 0.f, 0.f, 0.f};

  // Q fragments (+ r_w_bias) for AC, registers (wave wv owns rows [16wv,16wv+16))
  s16x8 qw[2];
  {
    int i = i0 + wv * 16 + c16;
    const u16* src = qkv + ((size_t)(i * 2 + b)) * 3072 + n * 64;
#pragma unroll
    for (int ks = 0; ks < 2; ++ks) {
      int d0 = ks * 32 + g * 8;
      u16x8 raw = *(const u16x8*)(src + d0);
      u16x8 wq;
#pragma unroll
      for (int e = 0; e < 8; ++e)
        wq[e] = f2bf(bf2f(raw[e]) + rwb[n * 64 + d0 + e]);
      qw[ks] = __builtin_bit_cast(s16x8, wq);
    }
  }
  // Q' (+ r_r_bias) rows i0..i0+79 into LDS (clamped past SEQ)
  for (int idx = tid; idx < 80 * 8; idx += 256) {
    int r = idx >> 3, cc = (idx & 7) * 8;
    int i = i0 + r;
    u16x8 outv;
    if (i < SEQ) {
      u16x8 raw = *(const u16x8*)(qkv + ((size_t)(i * 2 + b)) * 3072 + n * 64 + cc);
#pragma unroll
      for (int e = 0; e < 8; ++e)
        outv[e] = f2bf(bf2f(raw[e]) + rrb[n * 64 + cc + e]);
    } else {
#pragma unroll
      for (int e = 0; e < 8; ++e) outv[e] = 0;
    }
    *(u16x8*)&Qp[r][cc] = outv;
  }

  float m_prev[4], l_sum[4];
  f32x4 o_acc[4];
#pragma unroll
  for (int r = 0; r < 4; ++r) { m_prev[r] = -1e30f; l_sum[r] = 0.f; o_acc[r] = zero4; }

  for (int kt = 0; kt < 32; ++kt) {
    const int j0 = kt * 64;
    __syncthreads();
    // stage K tile
#pragma unroll
    for (int p = 0; p < 2; ++p) {
      int f = p * 256 + tid;
      int r = f >> 3, cc = (f & 7) * 8;
      *(u16x8*)&Kt[r][cc] =
          *(const u16x8*)(qkv + ((size_t)((j0 + r) * 2 + b)) * 3072 + 1024 + n * 64 + cc);
    }
    // stage V^T tile
#pragma unroll
    for (int p = 0; p < 2; ++p) {
      int f = p * 256 + tid;
      int r = f >> 3, cc = (f & 7) * 8;
      *(u16x8*)&Vt[r][cc] =
          *(const u16x8*)(vT + ((size_t)((b * 16 + n) * 64 + r)) * 2048 + j0 + cc);
    }
    // stage r_k band: u = j0-i0-63+w ; c = u<=0 ? u+2047 : u-2 ; c==-1 -> zeros
#pragma unroll
    for (int p = 0; p < 4; ++p) {
      int f = p * 256 + tid;
      int r = f >> 3, cc = (f & 7) * 8;
      int u = j0 - i0 - 63 + r;
      int c = (u <= 0) ? (u + (SEQ - 1)) : (u - 2);
      u16x8 v;
      if (c >= 0) v = *(const u16x8*)(rk + (size_t)c * 1024 + n * 64 + cc);
      else {
#pragma unroll
        for (int e = 0; e < 8; ++e) v[e] = 0;
      }
      *(u16x8*)&Rb[r][cc] = v;
    }
    __syncthreads();

    // AC = (Q+rw) @ K^T
    f32x4 sc[4];
#pragma unroll
    for (int fj = 0; fj < 4; ++fj) sc[fj] = zero4;
#pragma unroll
    for (int ks = 0; ks < 2; ++ks)
#pragma unroll
      for (int fj = 0; fj < 4; ++fj) {
        s16x8 bf = *(const s16x8*)&Kt[fj * 16 + c16][ks * 32 + g * 8];
        sc[fj] = __builtin_amdgcn_mfma_f32_16x16x32_bf16(qw[ks], bf, sc[fj], 0, 0, 0);
      }
    // QR band = (Q'+rr) @ Rband^T  (80 x 128), each wave does col-frags 2wv..2wv+1
#pragma unroll
    for (int rg = 0; rg < 5; ++rg) {
      s16x8 aq0 = *(const s16x8*)&Qp[rg * 16 + c16][g * 8];
      s16x8 aq1 = *(const s16x8*)&Qp[rg * 16 + c16][32 + g * 8];
#pragma unroll
      for (int c2 = 0; c2 < 2; ++c2) {
        int cf = wv * 2 + c2;
        f32x4 qr = zero4;
        s16x8 b0 = *(const s16x8*)&Rb[cf * 16 + c16][g * 8];
        s16x8 b1 = *(const s16x8*)&Rb[cf * 16 + c16][32 + g * 8];
        qr = __builtin_amdgcn_mfma_f32_16x16x32_bf16(aq0, b0, qr, 0, 0, 0);
        qr = __builtin_amdgcn_mfma_f32_16x16x32_bf16(aq1, b1, qr, 0, 0, 0);
#pragma unroll
        for (int reg = 0; reg < 4; ++reg)
          QRs[rg * 16 + g * 4 + reg][cf * 16 + c16] = f2bf(qr[reg]);
      }
    }
    __syncthreads();

    // gather BD (rel-shift) + online softmax
#pragma unroll
    for (int fj = 0; fj < 4; ++fj)
#pragma unroll
      for (int reg = 0; reg < 4; ++reg) {
        int ii = wv * 16 + g * 4 + reg;
        int jj = fj * 16 + c16;
        int u = (j0 + jj) - (i0 + ii);
        int rowp = ii + (u >= 1 ? 1 : 0);
        int w = jj - ii + 63;
        sc[fj][reg] += bf2f(QRs[rowp][w]);
      }
    float mt[4];
#pragma unroll
    for (int reg = 0; reg < 4; ++reg)
      mt[reg] = fmaxf(fmaxf(sc[0][reg], sc[1][reg]), fmaxf(sc[2][reg], sc[3][reg]));
#pragma unroll
    for (int off = 1; off < 16; off <<= 1)
#pragma unroll
      for (int reg = 0; reg < 4; ++reg)
        mt[reg] = fmaxf(mt[reg], __shfl_xor(mt[reg], off, 16));
    float al[4], rs[4];
#pragma unroll
    for (int reg = 0; reg < 4; ++reg) {
      float mn = fmaxf(m_prev[reg], mt[reg]);
      al[reg] = __builtin_amdgcn_exp2f((m_prev[reg] - mn) * KEXP);
      m_prev[reg] = mn;
      rs[reg] = 0.f;
    }
#pragma unroll
    for (int fj = 0; fj < 4; ++fj)
#pragma unroll
      for (int reg = 0; reg < 4; ++reg) {
        float p = __builtin_amdgcn_exp2f((sc[fj][reg] - m_prev[reg]) * KEXP);
        rs[reg] += p;
        Pt[wv * 16 + g * 4 + reg][fj * 16 + c16] = f2bf(p);
      }
#pragma unroll
    for (int off = 1; off < 16; off <<= 1)
#pragma unroll
      for (int reg = 0; reg < 4; ++reg)
        rs[reg] += __shfl_xor(rs[reg], off, 16);
#pragma unroll
    for (int reg = 0; reg < 4; ++reg)
      l_sum[reg] = l_sum[reg] * al[reg] + rs[reg];
#pragma unroll
    for (int fd = 0; fd < 4; ++fd)
#pragma unroll
      for (int reg = 0; reg < 4; ++reg)
        o_acc[fd][reg] *= al[reg];

    // PV: O += P @ V   (Pt write->read is same-wave; no barrier needed)
#pragma unroll
    for (int ks = 0; ks < 2; ++ks) {
      s16x8 pa = *(const s16x8*)&Pt[wv * 16 + c16][ks * 32 + g * 8];
#pragma unroll
      for (int fd = 0; fd < 4; ++fd) {
        s16x8 vb = *(const s16x8*)&Vt[fd * 16 + c16][ks * 32 + g * 8];
        o_acc[fd] = __builtin_amdgcn_mfma_f32_16x16x32_bf16(pa, vb, o_acc[fd], 0, 0, 0);
      }
    }
  }

#pragma unroll
  for (int reg = 0; reg < 4; ++reg) {
    float inv = 1.0f / l_sum[reg];
    int i = i0 + wv * 16 + g * 4 + reg;
    u16* dst = av + ((size_t)(i * 2 + b)) * 1024 + n * 64;
#pragma unroll
    for (int fd = 0; fd < 4; ++fd)
      dst[fd * 16 + c16] = f2bf(o_acc[fd][reg] * inv);
  }
}

// ---------------- LayerNorm over rows of tmp (= attn_out + h) ----------------
__global__ __launch_bounds__(256) void k_ln(const float* __restrict__ tmp,
                                            const float* __restrict__ gamma,
                                            const float* __restrict__ beta,
                                            float* __restrict__ out) {
  __shared__ float r1[4], r2[4];
  const int row = blockIdx.x, tid = threadIdx.x;
  const float* x = tmp + (size_t)row * 1024;
  float4 v = *(const float4*)(x + tid * 4);
  float s1 = v.x + v.y + v.z + v.w;
  float s2 = v.x * v.x + v.y * v.y + v.z * v.z + v.w * v.w;
#pragma unroll
  for (int off = 1; off < 64; off <<= 1) {
    s1 += __shfl_xor(s1, off, 64);
    s2 += __shfl_xor(s2, off, 64);
  }
  if ((tid & 63) == 0) { r1[tid >> 6] = s1; r2[tid >> 6] = s2; }
  __syncthreads();
  s1 = r1[0] + r1[1] + r1[2] + r1[3];
  s2 = r2[0] + r2[1] + r2[2] + r2[3];
  float mu = s1 * (1.f / 1024.f);
  float var = s2 * (1.f / 1024.f) - mu * mu;
  float rstd = rsqrtf(var + 1e-6f);
  float4 gm = *(const float4*)(gamma + tid * 4);
  float4 bt = *(const float4*)(beta + tid * 4);
  float4 o;
  o.x = (v.x - mu) * rstd * gm.x + bt.x;
  o.y = (v.y - mu) * rstd * gm.y + bt.y;
  o.z = (v.z - mu) * rstd * gm.z + bt.z;
  o.w = (v.w - mu) * rstd * gm.w + bt.w;
  *(float4*)(out + (size_t)row * 1024 + tid * 4) = o;
}

// ---------------- launch ----------------
extern "C" void kernel_launch(void* const* d_in, const int* in_sizes, int n_in,
                              void* d_out, int out_size, void* d_ws, size_t ws_size,
                              hipStream_t stream) {
  const float* h    = (const float*)d_in[0];
  const float* r    = (const float*)d_in[1];
  const float* rwb  = (const float*)d_in[2];
  const float* rrb  = (const float*)d_in[3];
  const float* Wqkv = (const float*)d_in[4];
  const float* Wr   = (const float*)d_in[5];
  const float* Wo   = (const float*)d_in[6];
  const float* gam  = (const float*)d_in[7];
  const float* bet  = (const float*)d_in[8];
  float* out = (float*)d_out;

  u16* hb     = (u16*)d_ws;                          // 4096*1024
  u16* Wqkv_t = hb + (size_t)4096 * 1024;            // 3072*1024
  u16* Wr_t   = Wqkv_t + (size_t)3072 * 1024;        // 1024*1024
  u16* Wo_t   = Wr_t + (size_t)1024 * 1024;          // 1024*1024
  u16* rb     = Wo_t + (size_t)1024 * 1024;          // 2048*1024
  u16* qkv    = rb + (size_t)2048 * 1024;            // 4096*3072
  u16* rk     = qkv + (size_t)4096 * 3072;           // 2048*1024
  u16* vT     = rk + (size_t)2048 * 1024;            // 2*16*64*2048
  u16* av     = vT + (size_t)2 * 16 * 64 * 2048;     // 4096*1024
  float* tmp  = (float*)(av + (size_t)4096 * 1024);  // 4096*1024 f32

  k_cvt<<<4096, 256, 0, stream>>>(h, hb, 4096 * 1024 / 4);
  k_cvt<<<2048, 256, 0, stream>>>(r, rb, 2048 * 1024 / 4);
  k_tcvt<<<dim3(48, 16), 256, 0, stream>>>(Wqkv, Wqkv_t, 1024, 3072);
  k_tcvt<<<dim3(16, 16), 256, 0, stream>>>(Wr, Wr_t, 1024, 1024);
  k_tcvt<<<dim3(16, 16), 256, 0, stream>>>(Wo, Wo_t, 1024, 1024);
  k_gemm_bt<0><<<dim3(32, 24), 256, 0, stream>>>(hb, Wqkv_t, qkv, nullptr, nullptr,
                                                 4096, 3072, 1024);
  k_gemm_bt<0><<<dim3(16, 8), 256, 0, stream>>>(rb, Wr_t, rk, nullptr, nullptr,
                                                2048, 1024, 1024);
  k_vt<<<dim3(32, 32), 256, 0, stream>>>(qkv, vT);
  k_attn<<<dim3(32, 32), 256, 0, stream>>>(qkv, rk, vT, rwb, rrb, av);
  k_gemm_bt<1><<<dim3(32, 8), 256, 0, stream>>>(av, Wo_t, nullptr, tmp, h,
                                                4096, 1024, 1024);
  k_ln<<<4096, 256, 0, stream>>>(tmp, gam, bet, out);
}

// Round 3
// 322.145 us; speedup vs baseline: 1.2133x; 1.2133x over previous
//
#include <hip/hip_runtime.h>
#include <hip/hip_bf16.h>

typedef unsigned short u16;
typedef __attribute__((ext_vector_type(8))) short s16x8;
typedef __attribute__((ext_vector_type(8))) unsigned short u16x8;
typedef __attribute__((ext_vector_type(4))) float f32x4;

#define SEQ 2048
#define KEXP 0.18033688011112042f  /* 0.125 * log2(e) */

__device__ __forceinline__ float bf2f(u16 x) {
  union { unsigned u; float f; } c; c.u = ((unsigned)x) << 16; return c.f;
}
// hardware bf16 convert (v_cvt_pk_bf16_f32 on gfx950)
__device__ __forceinline__ u16 f2bf(float f) {
  __hip_bfloat16 h = __float2bfloat16(f);
  return __builtin_bit_cast(u16, h);
}

// ---------------- fp32 -> bf16 flat convert ----------------
__global__ __launch_bounds__(256) void k_cvt(const float* __restrict__ src,
                                             u16* __restrict__ dst, int n4) {
  int i = blockIdx.x * 256 + threadIdx.x;
  if (i >= n4) return;
  float4 v = ((const float4*)src)[i];
  ((ushort4*)dst)[i] = make_ushort4(f2bf(v.x), f2bf(v.y), f2bf(v.z), f2bf(v.w));
}

// ---------------- fp32 [R][C] -> bf16 [C][R] transpose-convert ----------------
__global__ __launch_bounds__(256) void k_tcvt(const float* __restrict__ src,
                                              u16* __restrict__ dst, int R, int C) {
  __shared__ u16 T[64][72];
  int r0 = blockIdx.y * 64, c0 = blockIdx.x * 64;
  int tid = threadIdx.x;
#pragma unroll
  for (int p = 0; p < 4; ++p) {
    int f = p * 256 + tid;            // float4 id within 64x64 tile
    int r = f >> 4, cc = (f & 15) * 4;
    float4 v = *(const float4*)(src + (size_t)(r0 + r) * C + c0 + cc);
    T[r][cc + 0] = f2bf(v.x); T[r][cc + 1] = f2bf(v.y);
    T[r][cc + 2] = f2bf(v.z); T[r][cc + 3] = f2bf(v.w);
  }
  __syncthreads();
#pragma unroll
  for (int p = 0; p < 2; ++p) {
    int f = p * 256 + tid;            // u16x8 chunk id
    int c = f >> 3, rr = (f & 7) * 8;
    u16x8 v;
#pragma unroll
    for (int e = 0; e < 8; ++e) v[e] = T[rr + e][c];
    *(u16x8*)(dst + (size_t)(c0 + c) * R + r0 + rr) = v;
  }
}

// ---------------- C[M,N] = A[M,K] @ Bt[N,K]^T  (bf16 in, bf16 or f32+res out) ----
template <int RES>
__global__ __launch_bounds__(256) void k_gemm_bt(const u16* __restrict__ A,
                                                 const u16* __restrict__ Bt,
                                                 u16* __restrict__ Cb,
                                                 float* __restrict__ Cf,
                                                 const float* __restrict__ res,
                                                 int M, int N, int K) {
  __shared__ u16 As[128 * 72];
  __shared__ u16 Bs[128 * 72];
  const int tid = threadIdx.x;
  const int l = tid & 63, wv = tid >> 6;
  const int g = l >> 4, c16 = l & 15;
  const int m0 = blockIdx.x * 128, n0 = blockIdx.y * 128;
  const int wr = (wv >> 1) * 64, wc = (wv & 1) * 64;
  f32x4 acc[4][4] = {};
  for (int k0 = 0; k0 < K; k0 += 64) {
    __syncthreads();
    // 128 rows x 64 k = 1024 16B-chunks per matrix; 256 threads -> 4 iters
#pragma unroll
    for (int p = 0; p < 4; ++p) {
      int f = p * 256 + tid;
      int row = f >> 3, kb = (f & 7) * 8;
      u16x8 va = *(const u16x8*)(A + (size_t)(m0 + row) * K + k0 + kb);
      u16x8 vb = *(const u16x8*)(Bt + (size_t)(n0 + row) * K + k0 + kb);
      *(u16x8*)&As[row * 72 + kb] = va;
      *(u16x8*)&Bs[row * 72 + kb] = vb;
    }
    __syncthreads();
#pragma unroll
    for (int ks = 0; ks < 2; ++ks) {
      s16x8 af[4], bf[4];
#pragma unroll
      for (int fr = 0; fr < 4; ++fr)
        af[fr] = *(const s16x8*)&As[(wr + fr * 16 + c16) * 72 + ks * 32 + g * 8];
#pragma unroll
      for (int fc = 0; fc < 4; ++fc)
        bf[fc] = *(const s16x8*)&Bs[(wc + fc * 16 + c16) * 72 + ks * 32 + g * 8];
#pragma unroll
      for (int fr = 0; fr < 4; ++fr)
#pragma unroll
        for (int fc = 0; fc < 4; ++fc)
          acc[fr][fc] = __builtin_amdgcn_mfma_f32_16x16x32_bf16(af[fr], bf[fc],
                                                                acc[fr][fc], 0, 0, 0);
    }
  }
#pragma unroll
  for (int fr = 0; fr < 4; ++fr)
#pragma unroll
    for (int fc = 0; fc < 4; ++fc)
#pragma unroll
      for (int reg = 0; reg < 4; ++reg) {
        int row = m0 + wr + fr * 16 + g * 4 + reg;
        int col = n0 + wc + fc * 16 + c16;
        float v = acc[fr][fc][reg];
        if (RES) Cf[(size_t)row * N + col] = v + res[(size_t)row * N + col];
        else     Cb[(size_t)row * N + col] = f2bf(v);
      }
}

// ---------------- build V^T [b][n][d][j] from qkv ----------------
__global__ __launch_bounds__(256) void k_vt(const u16* __restrict__ qkv,
                                            u16* __restrict__ vT) {
  __shared__ u16 T[64][72];
  const int tid = threadIdx.x;
  const int j0 = blockIdx.x * 64;
  const int n = blockIdx.y & 15, b = blockIdx.y >> 4;
#pragma unroll
  for (int p = 0; p < 2; ++p) {
    int f = p * 256 + tid;
    int r = f >> 3, cc = (f & 7) * 8;
    *(u16x8*)&T[r][cc] =
        *(const u16x8*)(qkv + ((size_t)((j0 + r) * 2 + b)) * 3072 + 2048 + n * 64 + cc);
  }
  __syncthreads();
#pragma unroll
  for (int p = 0; p < 2; ++p) {
    int f = p * 256 + tid;
    int d = f >> 3, jc = (f & 7) * 8;
    u16x8 v;
#pragma unroll
    for (int e = 0; e < 8; ++e) v[e] = T[jc + e][d];
    *(u16x8*)(vT + ((size_t)((b * 16 + n) * 64 + d)) * 2048 + j0 + jc) = v;
  }
}

// ---------------- fused rel-attention (flash-style) ----------------
__global__ __launch_bounds__(256) void k_attn(const u16* __restrict__ qkv,
                                              const u16* __restrict__ rk,
                                              const u16* __restrict__ vT,
                                              const float* __restrict__ rwb,
                                              const float* __restrict__ rrb,
                                              u16* __restrict__ av) {
  __shared__ u16 Qp[80][72];     // Q + r_r_bias rows i0..i0+79
  __shared__ u16 KtPt[64][72];   // K tile [j][d] during AC; P (probs) during PV
  __shared__ u16 Vt[64][72];     // V^T tile [d][j]
  __shared__ u16 QRsT[128][90];  // QR band, TRANSPOSED: [w][row]

  const int tid = threadIdx.x;
  const int l = tid & 63, wv = tid >> 6;
  const int g = l >> 4, c16 = l & 15;
  const int i0 = blockIdx.x * 64;
  const int n = blockIdx.y & 15, b = blockIdx.y >> 4;
  const f32x4 zero4 = {0.f, 0.f, 0.f, 0.f};
  const s16x8 zero8 = {0, 0, 0, 0, 0, 0, 0, 0};

  // Q fragments (+ r_w_bias) for AC, registers (wave wv owns rows [16wv,16wv+16))
  s16x8 qw[2];
  {
    int i = i0 + wv * 16 + c16;
    const u16* src = qkv + ((size_t)(i * 2 + b)) * 3072 + n * 64;
#pragma unroll
    for (int ks = 0; ks < 2; ++ks) {
      int d0 = ks * 32 + g * 8;
      u16x8 raw = *(const u16x8*)(src + d0);
      u16x8 wq;
#pragma unroll
      for (int e = 0; e < 8; ++e)
        wq[e] = f2bf(bf2f(raw[e]) + rwb[n * 64 + d0 + e]);
      qw[ks] = __builtin_bit_cast(s16x8, wq);
    }
  }
  // Q' (+ r_r_bias) rows i0..i0+79 into LDS (clamped past SEQ)
  for (int idx = tid; idx < 80 * 8; idx += 256) {
    int r = idx >> 3, cc = (idx & 7) * 8;
    int i = i0 + r;
    u16x8 outv;
    if (i < SEQ) {
      u16x8 raw = *(const u16x8*)(qkv + ((size_t)(i * 2 + b)) * 3072 + n * 64 + cc);
#pragma unroll
      for (int e = 0; e < 8; ++e)
        outv[e] = f2bf(bf2f(raw[e]) + rrb[n * 64 + cc + e]);
    } else {
#pragma unroll
      for (int e = 0; e < 8; ++e) outv[e] = 0;
    }
    *(u16x8*)&Qp[r][cc] = outv;
  }

  float m_prev[4], l_sum[4];
  f32x4 o_acc[4];
#pragma unroll
  for (int r = 0; r < 4; ++r) { m_prev[r] = -1e30f; l_sum[r] = 0.f; o_acc[r] = zero4; }

  for (int kt = 0; kt < 32; ++kt) {
    const int j0 = kt * 64;
    __syncthreads();

    // direct-load QR B-fragments from global rk (L2-hot), issued early
    s16x8 rbf[2][2];
#pragma unroll
    for (int c2 = 0; c2 < 2; ++c2) {
      int wrow = (wv * 2 + c2) * 16 + c16;
      int u = j0 - i0 - 63 + wrow;
      int c = (u <= 0) ? (u + (SEQ - 1)) : (u - 2);
      const u16* p = rk + (size_t)(c < 0 ? 0 : c) * 1024 + n * 64;
      rbf[c2][0] = *(const s16x8*)(p + g * 8);
      rbf[c2][1] = *(const s16x8*)(p + 32 + g * 8);
      if (c < 0) { rbf[c2][0] = zero8; rbf[c2][1] = zero8; }
    }

    // stage K tile into KtPt
#pragma unroll
    for (int p = 0; p < 2; ++p) {
      int f = p * 256 + tid;
      int r = f >> 3, cc = (f & 7) * 8;
      *(u16x8*)&KtPt[r][cc] =
          *(const u16x8*)(qkv + ((size_t)((j0 + r) * 2 + b)) * 3072 + 1024 + n * 64 + cc);
    }
    // stage V^T tile
#pragma unroll
    for (int p = 0; p < 2; ++p) {
      int f = p * 256 + tid;
      int r = f >> 3, cc = (f & 7) * 8;
      *(u16x8*)&Vt[r][cc] =
          *(const u16x8*)(vT + ((size_t)((b * 16 + n) * 64 + r)) * 2048 + j0 + cc);
    }
    __syncthreads();

    // AC = (Q+rw) @ K^T
    f32x4 sc[4];
#pragma unroll
    for (int fj = 0; fj < 4; ++fj) sc[fj] = zero4;
#pragma unroll
    for (int ks = 0; ks < 2; ++ks)
#pragma unroll
      for (int fj = 0; fj < 4; ++fj) {
        s16x8 bf = *(const s16x8*)&KtPt[fj * 16 + c16][ks * 32 + g * 8];
        sc[fj] = __builtin_amdgcn_mfma_f32_16x16x32_bf16(qw[ks], bf, sc[fj], 0, 0, 0);
      }
    // QR band = (Q'+rr) @ Rband^T  (80 x 128), wave wv owns w-cols [32wv,32wv+32)
#pragma unroll
    for (int rg = 0; rg < 5; ++rg) {
      s16x8 aq0 = *(const s16x8*)&Qp[rg * 16 + c16][g * 8];
      s16x8 aq1 = *(const s16x8*)&Qp[rg * 16 + c16][32 + g * 8];
#pragma unroll
      for (int c2 = 0; c2 < 2; ++c2) {
        int wrow = (wv * 2 + c2) * 16 + c16;
        f32x4 qr = zero4;
        qr = __builtin_amdgcn_mfma_f32_16x16x32_bf16(aq0, rbf[c2][0], qr, 0, 0, 0);
        qr = __builtin_amdgcn_mfma_f32_16x16x32_bf16(aq1, rbf[c2][1], qr, 0, 0, 0);
        // transposed scatter, paired u32 writes (rows rg*16+g*4 .. +3)
        unsigned p0 = (unsigned)f2bf(qr[0]) | ((unsigned)f2bf(qr[1]) << 16);
        unsigned p1 = (unsigned)f2bf(qr[2]) | ((unsigned)f2bf(qr[3]) << 16);
        u16* base = &QRsT[wrow][rg * 16 + g * 4];
        *(unsigned*)(base) = p0;
        *(unsigned*)(base + 2) = p1;
      }
    }
    __syncthreads();

    // gather BD (rel-shift) + online softmax
#pragma unroll
    for (int fj = 0; fj < 4; ++fj)
#pragma unroll
      for (int reg = 0; reg < 4; ++reg) {
        int ii = wv * 16 + g * 4 + reg;
        int jj = fj * 16 + c16;
        int u = (j0 + jj) - (i0 + ii);
        int rowp = ii + (u >= 1 ? 1 : 0);
        int w = jj - ii + 63;
        sc[fj][reg] += bf2f(QRsT[w][rowp]);
      }
    float mt[4];
#pragma unroll
    for (int reg = 0; reg < 4; ++reg)
      mt[reg] = fmaxf(fmaxf(sc[0][reg], sc[1][reg]), fmaxf(sc[2][reg], sc[3][reg]));
#pragma unroll
    for (int off = 1; off < 16; off <<= 1)
#pragma unroll
      for (int reg = 0; reg < 4; ++reg)
        mt[reg] = fmaxf(mt[reg], __shfl_xor(mt[reg], off, 16));
    float al[4], rs[4];
#pragma unroll
    for (int reg = 0; reg < 4; ++reg) {
      float mn = fmaxf(m_prev[reg], mt[reg]);
      al[reg] = __builtin_amdgcn_exp2f((m_prev[reg] - mn) * KEXP);
      m_prev[reg] = mn;
      rs[reg] = 0.f;
    }
    // P tile: write into KtPt (Kt no longer needed; all AC reads done pre-barrier)
#pragma unroll
    for (int fj = 0; fj < 4; ++fj)
#pragma unroll
      for (int reg = 0; reg < 4; ++reg) {
        float p = __builtin_amdgcn_exp2f((sc[fj][reg] - m_prev[reg]) * KEXP);
        rs[reg] += p;
        KtPt[wv * 16 + g * 4 + reg][fj * 16 + c16] = f2bf(p);
      }
#pragma unroll
    for (int off = 1; off < 16; off <<= 1)
#pragma unroll
      for (int reg = 0; reg < 4; ++reg)
        rs[reg] += __shfl_xor(rs[reg], off, 16);
#pragma unroll
    for (int reg = 0; reg < 4; ++reg)
      l_sum[reg] = l_sum[reg] * al[reg] + rs[reg];
#pragma unroll
    for (int fd = 0; fd < 4; ++fd)
#pragma unroll
      for (int reg = 0; reg < 4; ++reg)
        o_acc[fd][reg] *= al[reg];

    // PV: O += P @ V   (P write->read is same-wave strip; no barrier needed)
#pragma unroll
    for (int ks = 0; ks < 2; ++ks) {
      s16x8 pa = *(const s16x8*)&KtPt[wv * 16 + c16][ks * 32 + g * 8];
#pragma unroll
      for (int fd = 0; fd < 4; ++fd) {
        s16x8 vb = *(const s16x8*)&Vt[fd * 16 + c16][ks * 32 + g * 8];
        o_acc[fd] = __builtin_amdgcn_mfma_f32_16x16x32_bf16(pa, vb, o_acc[fd], 0, 0, 0);
      }
    }
  }

#pragma unroll
  for (int reg = 0; reg < 4; ++reg) {
    float inv = 1.0f / l_sum[reg];
    int i = i0 + wv * 16 + g * 4 + reg;
    u16* dst = av + ((size_t)(i * 2 + b)) * 1024 + n * 64;
#pragma unroll
    for (int fd = 0; fd < 4; ++fd)
      dst[fd * 16 + c16] = f2bf(o_acc[fd][reg] * inv);
  }
}

// ---------------- LayerNorm over rows of tmp (= attn_out + h) ----------------
__global__ __launch_bounds__(256) void k_ln(const float* __restrict__ tmp,
                                            const float* __restrict__ gamma,
                                            const float* __restrict__ beta,
                                            float* __restrict__ out) {
  __shared__ float r1[4], r2[4];
  const int row = blockIdx.x, tid = threadIdx.x;
  const float* x = tmp + (size_t)row * 1024;
  float4 v = *(const float4*)(x + tid * 4);
  float s1 = v.x + v.y + v.z + v.w;
  float s2 = v.x * v.x + v.y * v.y + v.z * v.z + v.w * v.w;
#pragma unroll
  for (int off = 1; off < 64; off <<= 1) {
    s1 += __shfl_xor(s1, off, 64);
    s2 += __shfl_xor(s2, off, 64);
  }
  if ((tid & 63) == 0) { r1[tid >> 6] = s1; r2[tid >> 6] = s2; }
  __syncthreads();
  s1 = r1[0] + r1[1] + r1[2] + r1[3];
  s2 = r2[0] + r2[1] + r2[2] + r2[3];
  float mu = s1 * (1.f / 1024.f);
  float var = s2 * (1.f / 1024.f) - mu * mu;
  float rstd = rsqrtf(var + 1e-6f);
  float4 gm = *(const float4*)(gamma + tid * 4);
  float4 bt = *(const float4*)(beta + tid * 4);
  float4 o;
  o.x = (v.x - mu) * rstd * gm.x + bt.x;
  o.y = (v.y - mu) * rstd * gm.y + bt.y;
  o.z = (v.z - mu) * rstd * gm.z + bt.z;
  o.w = (v.w - mu) * rstd * gm.w + bt.w;
  *(float4*)(out + (size_t)row * 1024 + tid * 4) = o;
}

// ---------------- launch ----------------
extern "C" void kernel_launch(void* const* d_in, const int* in_sizes, int n_in,
                              void* d_out, int out_size, void* d_ws, size_t ws_size,
                              hipStream_t stream) {
  const float* h    = (const float*)d_in[0];
  const float* r    = (const float*)d_in[1];
  const float* rwb  = (const float*)d_in[2];
  const float* rrb  = (const float*)d_in[3];
  const float* Wqkv = (const float*)d_in[4];
  const float* Wr   = (const float*)d_in[5];
  const float* Wo   = (const float*)d_in[6];
  const float* gam  = (const float*)d_in[7];
  const float* bet  = (const float*)d_in[8];
  float* out = (float*)d_out;

  u16* hb     = (u16*)d_ws;                          // 4096*1024
  u16* Wqkv_t = hb + (size_t)4096 * 1024;            // 3072*1024
  u16* Wr_t   = Wqkv_t + (size_t)3072 * 1024;        // 1024*1024
  u16* Wo_t   = Wr_t + (size_t)1024 * 1024;          // 1024*1024
  u16* rb     = Wo_t + (size_t)1024 * 1024;          // 2048*1024
  u16* qkv    = rb + (size_t)2048 * 1024;            // 4096*3072
  u16* rk     = qkv + (size_t)4096 * 3072;           // 2048*1024
  u16* vT     = rk + (size_t)2048 * 1024;            // 2*16*64*2048
  u16* av     = vT + (size_t)2 * 16 * 64 * 2048;     // 4096*1024
  float* tmp  = (float*)(av + (size_t)4096 * 1024);  // 4096*1024 f32

  k_cvt<<<4096, 256, 0, stream>>>(h, hb, 4096 * 1024 / 4);
  k_cvt<<<2048, 256, 0, stream>>>(r, rb, 2048 * 1024 / 4);
  k_tcvt<<<dim3(48, 16), 256, 0, stream>>>(Wqkv, Wqkv_t, 1024, 3072);
  k_tcvt<<<dim3(16, 16), 256, 0, stream>>>(Wr, Wr_t, 1024, 1024);
  k_tcvt<<<dim3(16, 16), 256, 0, stream>>>(Wo, Wo_t, 1024, 1024);
  k_gemm_bt<0><<<dim3(32, 24), 256, 0, stream>>>(hb, Wqkv_t, qkv, nullptr, nullptr,
                                                 4096, 3072, 1024);
  k_gemm_bt<0><<<dim3(16, 8), 256, 0, stream>>>(rb, Wr_t, rk, nullptr, nullptr,
                                                2048, 1024, 1024);
  k_vt<<<dim3(32, 32), 256, 0, stream>>>(qkv, vT);
  k_attn<<<dim3(32, 32), 256, 0, stream>>>(qkv, rk, vT, rwb, rrb, av);
  k_gemm_bt<1><<<dim3(32, 8), 256, 0, stream>>>(av, Wo_t, nullptr, tmp, h,
                                                4096, 1024, 1024);
  k_ln<<<4096, 256, 0, stream>>>(tmp, gam, bet, out);
}